// Round 1
// baseline (129.454 us; speedup 1.0000x reference)
//
#include <hip/hip_runtime.h>

// SpMM: out[r, :] = sum_{e: row[e]==r} vals[e] * embeds[col[e], :]
// N_NODES=50000, N_EDGES=800000, D=64. row_idx is SORTED (contiguous segments).
//
// Strategy: one wave (64 lanes) per 64-edge contiguous chunk.
//   lane = feature index d  -> embeds[c*64 + d] is a coalesced 256B wave read.
//   Edge metadata loaded coalesced (lane i loads edge e0+i), then broadcast
//   one edge at a time via __shfl. Register-accumulate while row unchanged;
//   atomicAdd flush only at row boundaries (~(N_NODES + n_waves) flushes).

constexpr int N_NODES = 50000;
constexpr int N_EDGES = 800000;
constexpr int D_FEAT  = 64;
constexpr int EDGES_PER_WAVE = 64;

__global__ __launch_bounds__(256) void gcn_spmm_kernel(
    const int*   __restrict__ row_idx,
    const int*   __restrict__ col_idx,
    const float* __restrict__ vals,
    const float* __restrict__ embeds,
    float*       __restrict__ out)
{
    const int gtid = blockIdx.x * blockDim.x + threadIdx.x;
    const int wave = gtid >> 6;         // global wave id
    const int lane = threadIdx.x & 63;  // feature index

    const int e0 = wave * EDGES_PER_WAVE;
    if (e0 >= N_EDGES) return;
    const int e1 = (e0 + EDGES_PER_WAVE < N_EDGES) ? e0 + EDGES_PER_WAVE : N_EDGES;
    const int n  = e1 - e0;

    // Coalesced edge-metadata load: lane i holds edge e0+i.
    int   my_r = 0, my_c = 0;
    float my_v = 0.f;
    if (lane < n) {
        my_r = row_idx[e0 + lane];
        my_c = col_idx[e0 + lane];
        my_v = vals[e0 + lane];
    }

    float acc    = 0.f;
    int   prev_r = -1;

    for (int j = 0; j < n; ++j) {
        const int   r = __shfl(my_r, j);
        const int   c = __shfl(my_c, j);
        const float v = __shfl(my_v, j);
        if (r != prev_r) {
            if (prev_r >= 0) atomicAdd(&out[prev_r * D_FEAT + lane], acc);
            acc    = 0.f;
            prev_r = r;
        }
        acc += v * embeds[c * D_FEAT + lane];   // coalesced 256B wave read
    }
    if (prev_r >= 0) atomicAdd(&out[prev_r * D_FEAT + lane], acc);
}

extern "C" void kernel_launch(void* const* d_in, const int* in_sizes, int n_in,
                              void* d_out, int out_size, void* d_ws, size_t ws_size,
                              hipStream_t stream) {
    const int*   row_idx = (const int*)  d_in[0];
    const int*   col_idx = (const int*)  d_in[1];
    const float* vals    = (const float*)d_in[2];
    const float* embeds  = (const float*)d_in[3];
    float*       out     = (float*)      d_out;

    // Harness re-poisons d_out with 0xAA before every timed launch.
    hipMemsetAsync(out, 0, (size_t)out_size * sizeof(float), stream);

    const int n_waves  = (N_EDGES + EDGES_PER_WAVE - 1) / EDGES_PER_WAVE; // 12500
    const int block    = 256;                                             // 4 waves
    const int n_blocks = (n_waves * 64 + block - 1) / block;              // 3125

    gcn_spmm_kernel<<<n_blocks, block, 0, stream>>>(row_idx, col_idx, vals, embeds, out);
}

// Round 2
// 103.528 us; speedup vs baseline: 1.2504x; 1.2504x over previous
//
#include <hip/hip_runtime.h>

// SpMM: out[r, :] = sum_{e: row[e]==r} vals[e] * embeds[col[e], :]
// N_NODES=50000, N_EDGES=800000, D=64. row_idx is SORTED.
//
// Two-phase CSR plan:
//   Phase 1: build row_ptr[N_NODES+1] in d_ws (thread per edge marks starts).
//   Phase 2: one wave per row, lane = feature index.
//     - row constant per wave -> no atomics, no flush branch, plain store
//     - edge metadata loaded coalesced then __shfl-broadcast
//     - inner loop unrolled x4 with 4 independent accumulators -> 4 gather
//       loads in flight per wave (latency hiding; was 1 in round 1)
//     - every row written (empty rows store 0) -> no output memset needed

constexpr int N_NODES = 50000;
constexpr int N_EDGES = 800000;
constexpr int D_FEAT  = 64;

__global__ __launch_bounds__(256) void build_row_ptr_kernel(
    const int* __restrict__ row_idx,
    int*       __restrict__ row_ptr)
{
    const int e = blockIdx.x * blockDim.x + threadIdx.x;
    if (e >= N_EDGES) return;
    const int r     = row_idx[e];
    const int rprev = (e == 0) ? -1 : row_idx[e - 1];
    // Rows (rprev, r] all start at edge e (fills empty-row gaps too).
    for (int q = rprev + 1; q <= r; ++q) row_ptr[q] = e;
    if (e == N_EDGES - 1) {
        for (int q = r + 1; q <= N_NODES; ++q) row_ptr[q] = N_EDGES;
    }
}

__global__ __launch_bounds__(256) void gcn_spmm_rows_kernel(
    const int*   __restrict__ row_ptr,
    const int*   __restrict__ col_idx,
    const float* __restrict__ vals,
    const float* __restrict__ embeds,
    float*       __restrict__ out)
{
    const int gtid = blockIdx.x * blockDim.x + threadIdx.x;
    const int row  = gtid >> 6;          // one wave per row
    const int lane = threadIdx.x & 63;   // feature index
    if (row >= N_NODES) return;

    const int s = row_ptr[row];
    const int e = row_ptr[row + 1];

    float a0 = 0.f, a1 = 0.f, a2 = 0.f, a3 = 0.f;

    for (int base = s; base < e; base += 64) {
        const int n = (e - base < 64) ? (e - base) : 64;

        // Coalesced metadata load: lane i holds edge base+i.
        int   c = 0;
        float v = 0.f;
        if (lane < n) {
            c = col_idx[base + lane];
            v = vals[base + lane];
        }

        int j = 0;
        for (; j + 4 <= n; j += 4) {
            const int   c0 = __shfl(c, j);
            const int   c1 = __shfl(c, j + 1);
            const int   c2 = __shfl(c, j + 2);
            const int   c3 = __shfl(c, j + 3);
            const float v0 = __shfl(v, j);
            const float v1 = __shfl(v, j + 1);
            const float v2 = __shfl(v, j + 2);
            const float v3 = __shfl(v, j + 3);
            // 4 independent gathers in flight
            const float g0 = embeds[c0 * D_FEAT + lane];
            const float g1 = embeds[c1 * D_FEAT + lane];
            const float g2 = embeds[c2 * D_FEAT + lane];
            const float g3 = embeds[c3 * D_FEAT + lane];
            a0 += v0 * g0;
            a1 += v1 * g1;
            a2 += v2 * g2;
            a3 += v3 * g3;
        }
        for (; j < n; ++j) {
            const int   cj = __shfl(c, j);
            const float vj = __shfl(v, j);
            a0 += vj * embeds[cj * D_FEAT + lane];
        }
    }

    out[row * D_FEAT + lane] = (a0 + a1) + (a2 + a3);  // plain coalesced store
}

extern "C" void kernel_launch(void* const* d_in, const int* in_sizes, int n_in,
                              void* d_out, int out_size, void* d_ws, size_t ws_size,
                              hipStream_t stream) {
    const int*   row_idx = (const int*)  d_in[0];
    const int*   col_idx = (const int*)  d_in[1];
    const float* vals    = (const float*)d_in[2];
    const float* embeds  = (const float*)d_in[3];
    float*       out     = (float*)      d_out;
    int*         row_ptr = (int*)        d_ws;   // N_NODES+1 ints = ~200 KB

    // Phase 1: CSR row pointers.
    {
        const int block  = 256;
        const int blocks = (N_EDGES + block - 1) / block;  // 3125
        build_row_ptr_kernel<<<blocks, block, 0, stream>>>(row_idx, row_ptr);
    }

    // Phase 2: one wave per row. Every output row is written -> no memset.
    {
        const int block  = 256;
        const int blocks = (N_NODES * 64 + block - 1) / block;  // 12500
        gcn_spmm_rows_kernel<<<blocks, block, 0, stream>>>(row_ptr, col_idx, vals,
                                                           embeds, out);
    }
}

// Round 3
// 101.345 us; speedup vs baseline: 1.2774x; 1.0215x over previous
//
#include <hip/hip_runtime.h>

// SpMM: out[r, :] = sum_{e: row[e]==r} vals[e] * embeds[col[e], :]
// N_NODES=50000, N_EDGES=800000, D=64. row_idx is SORTED.
//
// Phase 1: build row_ptr[N_NODES+1] in d_ws.
// Phase 2: one wave per row. Lane layout: q = lane>>4 (edge slot within a
//   4-edge group), f = lane&15 (float4 feature chunk). Each lane loads a
//   float4 of the embeds row -> ONE wave load instruction gathers 4 full
//   256B embeds rows (4 edges). No shuffles in the inner loop (metadata
//   loaded directly; same-address lanes coalesce). Unroll x2 -> 2KB of
//   gather traffic in flight per wave. Cross-quarter butterfly (shfl_xor
//   16/32) at the end; quarter 0 does a single 256B float4 store per row.
//   Every row is written (empty rows -> 0), so no output memset.

constexpr int N_NODES = 50000;
constexpr int N_EDGES = 800000;
constexpr int D_FEAT  = 64;

__global__ __launch_bounds__(256) void build_row_ptr_kernel(
    const int* __restrict__ row_idx,
    int*       __restrict__ row_ptr)
{
    const int e = blockIdx.x * blockDim.x + threadIdx.x;
    if (e >= N_EDGES) return;
    const int r     = row_idx[e];
    const int rprev = (e == 0) ? -1 : row_idx[e - 1];
    for (int q = rprev + 1; q <= r; ++q) row_ptr[q] = e;   // fills empty rows too
    if (e == N_EDGES - 1) {
        for (int q = r + 1; q <= N_NODES; ++q) row_ptr[q] = N_EDGES;
    }
}

__global__ __launch_bounds__(256) void gcn_spmm_rows_kernel(
    const int*   __restrict__ row_ptr,
    const int*   __restrict__ col_idx,
    const float* __restrict__ vals,
    const float* __restrict__ embeds,
    float*       __restrict__ out)
{
    const int gtid = blockIdx.x * blockDim.x + threadIdx.x;
    const int row  = gtid >> 6;          // one wave per row
    if (row >= N_NODES) return;
    const int lane = threadIdx.x & 63;
    const int q    = lane >> 4;          // edge slot within 4-edge group
    const int f    = lane & 15;          // float4 feature chunk

    const int s = row_ptr[row];
    const int e = row_ptr[row + 1];

    const float4* __restrict__ emb4 = (const float4*)embeds;  // stride 16 per row

    float4 a0 = make_float4(0.f, 0.f, 0.f, 0.f);
    float4 a1 = make_float4(0.f, 0.f, 0.f, 0.f);

    int base = s + q;
    // Main loop: 8 edges per wave-iteration (2 per quarter, independent).
    for (; base + 4 < e; base += 8) {
        const int   c0 = col_idx[base];
        const float v0 = vals[base];
        const int   c1 = col_idx[base + 4];
        const float v1 = vals[base + 4];
        const float4 g0 = emb4[c0 * 16 + f];   // 2 independent 1KB wave gathers
        const float4 g1 = emb4[c1 * 16 + f];
        a0.x += v0 * g0.x; a0.y += v0 * g0.y; a0.z += v0 * g0.z; a0.w += v0 * g0.w;
        a1.x += v1 * g1.x; a1.y += v1 * g1.y; a1.z += v1 * g1.z; a1.w += v1 * g1.w;
    }
    // Tail: at most one edge left in this quarter's stride-4 sequence.
    if (base < e) {
        const int   c0 = col_idx[base];
        const float v0 = vals[base];
        const float4 g0 = emb4[c0 * 16 + f];
        a0.x += v0 * g0.x; a0.y += v0 * g0.y; a0.z += v0 * g0.z; a0.w += v0 * g0.w;
    }

    float x = a0.x + a1.x;
    float y = a0.y + a1.y;
    float z = a0.z + a1.z;
    float w = a0.w + a1.w;

    // Butterfly across the 4 quarters (lanes differing in bits 4,5).
    x += __shfl_xor(x, 16); x += __shfl_xor(x, 32);
    y += __shfl_xor(y, 16); y += __shfl_xor(y, 32);
    z += __shfl_xor(z, 16); z += __shfl_xor(z, 32);
    w += __shfl_xor(w, 16); w += __shfl_xor(w, 32);

    if (q == 0) {
        ((float4*)out)[row * 16 + f] = make_float4(x, y, z, w);  // 256B store
    }
}

extern "C" void kernel_launch(void* const* d_in, const int* in_sizes, int n_in,
                              void* d_out, int out_size, void* d_ws, size_t ws_size,
                              hipStream_t stream) {
    const int*   row_idx = (const int*)  d_in[0];
    const int*   col_idx = (const int*)  d_in[1];
    const float* vals    = (const float*)d_in[2];
    const float* embeds  = (const float*)d_in[3];
    float*       out     = (float*)      d_out;
    int*         row_ptr = (int*)        d_ws;   // N_NODES+1 ints = ~200 KB

    {
        const int block  = 256;
        const int blocks = (N_EDGES + block - 1) / block;  // 3125
        build_row_ptr_kernel<<<blocks, block, 0, stream>>>(row_idx, row_ptr);
    }
    {
        const int block  = 256;
        const int blocks = (N_NODES * 64 + block - 1) / block;  // 12500
        gcn_spmm_rows_kernel<<<blocks, block, 0, stream>>>(row_ptr, col_idx, vals,
                                                           embeds, out);
    }
}